// Round 1
// baseline (4183.001 us; speedup 1.0000x reference)
//
#include <hip/hip_runtime.h>
#include <hip/hip_bf16.h>
#include <math.h>

// Problem constants
#define BB 2
#define SS 2048
#define EE 2048
#define HH 16
#define DD 128
#define FF 6144   // 3*E

// ---------------------------------------------------------------------------
// Stage 1 & 4: tiled fp32 GEMM:  C[m][n] = sum_k A[m][k] * Bt[n][k] + bias[n]
// A: MxK row-major, Bt: NxK row-major (i.e. B transposed), C: MxN row-major.
// 64x64 tile, BK=16, 256 threads, 4x4 accumulators per thread.
// ---------------------------------------------------------------------------
#define BM 64
#define BN 64
#define BK 16

__global__ __launch_bounds__(256) void gemm_bias(
    const float* __restrict__ A, const float* __restrict__ Bt,
    const float* __restrict__ bias, float* __restrict__ C,
    int M, int N, int K) {
  __shared__ float As[BK][BM + 4];
  __shared__ float Bs[BK][BN + 4];
  const int tid = threadIdx.x;
  const int m0 = blockIdx.y * BM;
  const int n0 = blockIdx.x * BN;
  const int tx = tid & 15;       // 0..15  -> n sub-tile
  const int ty = tid >> 4;       // 0..15  -> m sub-tile
  const int lr = tid >> 2;       // 0..63  load row
  const int lk = (tid & 3) * 4;  // 0,4,8,12 load k offset

  float acc[4][4] = {};

  for (int k0 = 0; k0 < K; k0 += BK) {
    const float4 av = *(const float4*)(A  + (size_t)(m0 + lr) * K + k0 + lk);
    const float4 bv = *(const float4*)(Bt + (size_t)(n0 + lr) * K + k0 + lk);
    As[lk + 0][lr] = av.x; As[lk + 1][lr] = av.y;
    As[lk + 2][lr] = av.z; As[lk + 3][lr] = av.w;
    Bs[lk + 0][lr] = bv.x; Bs[lk + 1][lr] = bv.y;
    Bs[lk + 2][lr] = bv.z; Bs[lk + 3][lr] = bv.w;
    __syncthreads();
#pragma unroll
    for (int k = 0; k < BK; ++k) {
      float a[4], b[4];
#pragma unroll
      for (int i = 0; i < 4; ++i) a[i] = As[k][ty * 4 + i];
#pragma unroll
      for (int j = 0; j < 4; ++j) b[j] = Bs[k][tx * 4 + j];
#pragma unroll
      for (int i = 0; i < 4; ++i)
#pragma unroll
        for (int j = 0; j < 4; ++j) acc[i][j] += a[i] * b[j];
    }
    __syncthreads();
  }

#pragma unroll
  for (int i = 0; i < 4; ++i) {
    const int m = m0 + ty * 4 + i;
#pragma unroll
    for (int j = 0; j < 4; ++j) {
      const int n = n0 + tx * 4 + j;
      C[(size_t)m * N + n] = acc[i][j] + bias[n];
    }
  }
}

// ---------------------------------------------------------------------------
// Stage 2: rotary embedding applied in-place to q and k inside the qkv buffer.
// qkv layout: [B][S][3][H][D], one thread per (b,s,h,d) with d in [0,64).
// ---------------------------------------------------------------------------
__global__ __launch_bounds__(256) void rotary_kernel(float* __restrict__ qkv) {
  const int idx = blockIdx.x * blockDim.x + threadIdx.x;
  const int d = idx & 63;
  const int h = (idx >> 6) & (HH - 1);
  const int s = (idx >> 10) & (SS - 1);
  const int b = idx >> 21;

  const float inv_freq = powf(10000.0f, -(float)d / 64.0f);
  const float freq = (float)s * inv_freq;
  const float c = cosf(freq);
  const float sn = sinf(freq);

  const size_t base = ((size_t)b * SS + s) * FF + h * DD + d;
  float* q = qkv + base;           // which = 0
  float* k = qkv + base + EE;      // which = 1

  const float q1 = q[0], q2 = q[64];
  q[0]  = q1 * c - q2 * sn;
  q[64] = q2 * c + q1 * sn;
  const float k1 = k[0], k2 = k[64];
  k[0]  = k1 * c - k2 * sn;
  k[64] = k2 * c + k1 * sn;
}

// ---------------------------------------------------------------------------
// Stage 3: flash-style causal attention.
// One block per (b, h, q-tile of 64 rows). 256 threads:
//   thread tid -> q row r = tid>>2 (0..63), d-slice p = tid&3 (32 of 128 dims).
// K/V staged in LDS in 32-row tiles; scores reduced across the row's 4
// adjacent lanes via __shfl_xor; online softmax state replicated per-quad.
// LDS: Ks 16KB + Vs 16KB + St 8KB = 40KB -> 4 blocks/CU.
// ---------------------------------------------------------------------------
#define TQ 64
#define TK 32

__global__ __launch_bounds__(256) void attn_kernel(
    const float* __restrict__ qkv, float* __restrict__ ctx) {
  __shared__ float Ks[TK][DD];
  __shared__ float Vs[TK][DD];
  __shared__ float St[TK][TQ];  // transposed: St[c][r], conflict-free

  const int qt = blockIdx.x;
  const int h  = blockIdx.y;
  const int b  = blockIdx.z;
  const int tid = threadIdx.x;
  const int r = tid >> 2;   // q row within tile
  const int p = tid & 3;    // d-slice index
  const int q0 = qt * TQ;
  const float scale = 0.08838834764831845f;  // 1/sqrt(128)

  // Load q row slice into registers, pre-scaled.
  float qreg[32];
  {
    const size_t qbase = ((size_t)b * SS + q0 + r) * FF + h * DD + p * 32;
#pragma unroll
    for (int j = 0; j < 32; j += 4) {
      const float4 v = *(const float4*)(qkv + qbase + j);
      qreg[j]     = v.x * scale;
      qreg[j + 1] = v.y * scale;
      qreg[j + 2] = v.z * scale;
      qreg[j + 3] = v.w * scale;
    }
  }

  float oacc[32] = {};
  float m_i = -INFINITY, l_i = 0.0f;

  // K/V tile load mapping: row c = tid>>3 (0..31), sub = tid&7 (16 floats).
  const int lc = tid >> 3;
  const int lsub = (tid & 7) * 16;

  const int nkt = 2 * (qt + 1);  // k-tiles needed to cover rows 0..q0+63
  for (int kt = 0; kt < nkt; ++kt) {
    const int k0 = kt * TK;
    {
      const size_t kbase =
          ((size_t)b * SS + k0 + lc) * FF + EE + h * DD + lsub;
      const size_t vbase = kbase + EE;  // which=2
#pragma unroll
      for (int j = 0; j < 16; j += 4) {
        *(float4*)(&Ks[lc][lsub + j]) = *(const float4*)(qkv + kbase + j);
        *(float4*)(&Vs[lc][lsub + j]) = *(const float4*)(qkv + vbase + j);
      }
    }
    __syncthreads();

    // Scores for this tile; each lane computes a 32-dim partial dot, quad
    // shuffle-reduce gives the full 128-dim dot in all 4 lanes.
    float tmax = -INFINITY;
    for (int c = 0; c < TK; ++c) {
      float partial = 0.0f;
      const float4* kr = (const float4*)&Ks[c][p * 32];
#pragma unroll
      for (int jj = 0; jj < 8; ++jj) {
        const float4 kv = kr[jj];
        partial += qreg[4 * jj] * kv.x + qreg[4 * jj + 1] * kv.y +
                   qreg[4 * jj + 2] * kv.z + qreg[4 * jj + 3] * kv.w;
      }
      partial += __shfl_xor(partial, 1);
      partial += __shfl_xor(partial, 2);
      const float sc = (k0 + c <= q0 + r) ? partial : -INFINITY;
      if (p == 0) St[c][r] = sc;
      tmax = fmaxf(tmax, sc);
    }

    // Online softmax update (identical computation in all 4 lanes of a row).
    const float mnew = fmaxf(m_i, tmax);
    const float alpha = expf(m_i - mnew);  // first tile: exp(-inf)=0
    l_i *= alpha;
#pragma unroll
    for (int j = 0; j < 32; ++j) oacc[j] *= alpha;

    for (int c = 0; c < TK; ++c) {
      const float pv = expf(St[c][r] - mnew);  // masked -> exp(-inf)=0
      l_i += pv;
      const float4* vr = (const float4*)&Vs[c][p * 32];
#pragma unroll
      for (int jj = 0; jj < 8; ++jj) {
        const float4 vv = vr[jj];
        oacc[4 * jj]     += pv * vv.x;
        oacc[4 * jj + 1] += pv * vv.y;
        oacc[4 * jj + 2] += pv * vv.z;
        oacc[4 * jj + 3] += pv * vv.w;
      }
    }
    m_i = mnew;
    __syncthreads();
  }

  const float inv_l = 1.0f / l_i;
  const size_t obase = ((size_t)b * SS + q0 + r) * EE + h * DD + p * 32;
#pragma unroll
  for (int j = 0; j < 32; j += 4) {
    float4 v;
    v.x = oacc[j] * inv_l;
    v.y = oacc[j + 1] * inv_l;
    v.z = oacc[j + 2] * inv_l;
    v.w = oacc[j + 3] * inv_l;
    *(float4*)(ctx + obase + j) = v;
  }
}

// ---------------------------------------------------------------------------
// Launch
// ---------------------------------------------------------------------------
extern "C" void kernel_launch(void* const* d_in, const int* in_sizes, int n_in,
                              void* d_out, int out_size, void* d_ws,
                              size_t ws_size, hipStream_t stream) {
  const float* x    = (const float*)d_in[0];
  const float* wqkv = (const float*)d_in[1];
  const float* bqkv = (const float*)d_in[2];
  const float* wout = (const float*)d_in[3];
  const float* bout = (const float*)d_in[4];
  float* out = (float*)d_out;

  float* qkv = (float*)d_ws;                       // B*S*3E floats = 100.7 MB
  float* ctx = qkv + (size_t)BB * SS * FF;         // B*S*E floats  =  33.6 MB

  const int M = BB * SS;  // 4096

  // 1) QKV projection: (4096 x 2048) @ (2048 x 6144) + bias
  {
    dim3 grid(FF / BN, M / BM);
    gemm_bias<<<grid, 256, 0, stream>>>(x, wqkv, bqkv, qkv, M, FF, EE);
  }
  // 2) rotary on q, k
  {
    const int total = BB * SS * HH * 64;
    rotary_kernel<<<total / 256, 256, 0, stream>>>(qkv);
  }
  // 3) causal attention -> ctx
  {
    dim3 grid(SS / TQ, HH, BB);
    attn_kernel<<<grid, 256, 0, stream>>>(qkv, ctx);
  }
  // 4) output projection: (4096 x 2048) @ (2048 x 2048) + bias
  {
    dim3 grid(EE / BN, M / BM);
    gemm_bias<<<grid, 256, 0, stream>>>(ctx, wout, bout, out, M, EE, EE);
  }
}

// Round 2
// 2491.672 us; speedup vs baseline: 1.6788x; 1.6788x over previous
//
#include <hip/hip_runtime.h>
#include <math.h>

// Problem constants
#define BB 2
#define SS 2048
#define EE 2048
#define HH 16
#define DD 128
#define FF 6144   // 3*E

typedef __attribute__((ext_vector_type(8))) short short8;
typedef __attribute__((ext_vector_type(4))) float floatx4;

static __device__ __forceinline__ unsigned short f2bf(float x) {
  unsigned u = __float_as_uint(x);
  u += 0x7fffu + ((u >> 16) & 1u);
  return (unsigned short)(u >> 16);
}
static __device__ __forceinline__ float bf2f(unsigned short h) {
  return __uint_as_float((unsigned)h << 16);
}

#define GLOAD_LDS16(gp, lp)                                       \
  __builtin_amdgcn_global_load_lds(                               \
      (const __attribute__((address_space(1))) void*)(gp),        \
      (__attribute__((address_space(3))) void*)(lp), 16, 0, 0)

// ---------------------------------------------------------------------------
// fp32 -> bf16 cast (float4 in, ushort4 out)
// ---------------------------------------------------------------------------
__global__ __launch_bounds__(256) void cast_f32_bf16(
    const float* __restrict__ in, unsigned short* __restrict__ out, int n4) {
  const int i = blockIdx.x * 256 + threadIdx.x;
  if (i >= n4) return;
  const float4 v = ((const float4*)in)[i];
  ushort4 o;
  o.x = f2bf(v.x); o.y = f2bf(v.y); o.z = f2bf(v.z); o.w = f2bf(v.w);
  ((ushort4*)out)[i] = o;
}

// ---------------------------------------------------------------------------
// bf16 MFMA GEMM (m97 structure): C[m][n] = sum_k A[m][k]*Bt[n][k] + bias[n]
// A: MxK bf16 row-major. Bt: NxK bf16 row-major. 128x128 tile, BK=32,
// 256 threads = 4 waves, each wave a 64x64 quadrant = 4x4 frags of 16x16x32.
// ---------------------------------------------------------------------------
static __device__ __forceinline__ void store_out(float* p, float v) { *p = v; }
static __device__ __forceinline__ void store_out(unsigned short* p, float v) {
  *p = f2bf(v);
}

template <typename OutT>
__global__ __launch_bounds__(256) void gemm_bf16_mfma(
    const unsigned short* __restrict__ A, const unsigned short* __restrict__ Bt,
    const float* __restrict__ bias, OutT* __restrict__ C,
    int M, int N, int K) {
  __shared__ unsigned short As[128][32];
  __shared__ unsigned short Bs[128][32];
  const int tid = threadIdx.x;
  const int L = tid & 63;
  const int w = tid >> 6;
  const int m0 = blockIdx.y * 128;
  const int n0 = blockIdx.x * 128;

  const int i0 = w * 2;
  const int lrow = L >> 2;
  const int lcol = (L & 3) * 8;
  const size_t a_off0 = (size_t)(m0 + (i0 + 0) * 16 + lrow) * K + lcol;
  const size_t a_off1 = (size_t)(m0 + (i0 + 1) * 16 + lrow) * K + lcol;
  const size_t b_off0 = (size_t)(n0 + (i0 + 0) * 16 + lrow) * K + lcol;
  const size_t b_off1 = (size_t)(n0 + (i0 + 1) * 16 + lrow) * K + lcol;

  const int wr = (w >> 1) * 64;
  const int wc = (w & 1) * 64;
  const int lane16 = L & 15;
  const int quad = L >> 4;

  floatx4 acc[4][4] = {};

  for (int k0 = 0; k0 < K; k0 += 32) {
    __syncthreads();
    GLOAD_LDS16(A + a_off0 + k0, &As[(i0 + 0) * 16][0]);
    GLOAD_LDS16(A + a_off1 + k0, &As[(i0 + 1) * 16][0]);
    GLOAD_LDS16(Bt + b_off0 + k0, &Bs[(i0 + 0) * 16][0]);
    GLOAD_LDS16(Bt + b_off1 + k0, &Bs[(i0 + 1) * 16][0]);
    __syncthreads();

    short8 a[4], b[4];
#pragma unroll
    for (int mi = 0; mi < 4; ++mi)
      a[mi] = *(const short8*)(&As[wr + mi * 16 + lane16][quad * 8]);
#pragma unroll
    for (int ni = 0; ni < 4; ++ni)
      b[ni] = *(const short8*)(&Bs[wc + ni * 16 + lane16][quad * 8]);
#pragma unroll
    for (int mi = 0; mi < 4; ++mi)
#pragma unroll
      for (int ni = 0; ni < 4; ++ni)
        acc[mi][ni] = __builtin_amdgcn_mfma_f32_16x16x32_bf16(
            a[mi], b[ni], acc[mi][ni], 0, 0, 0);
  }

  // C/D layout: col=lane&15, row=quad*4+reg (m89/m91 verified)
#pragma unroll
  for (int ni = 0; ni < 4; ++ni) {
    const int col = n0 + wc + ni * 16 + lane16;
    const float bv = bias[col];
#pragma unroll
    for (int mi = 0; mi < 4; ++mi) {
      const int row = m0 + wr + mi * 16 + quad * 4;
#pragma unroll
      for (int r = 0; r < 4; ++r)
        store_out(&C[(size_t)(row + r) * N + col], acc[mi][ni][r] + bv);
    }
  }
}

// ---------------------------------------------------------------------------
// Rotary on bf16 qkv in place. qkv layout [B][S][3][H][D] bf16.
// ---------------------------------------------------------------------------
__global__ __launch_bounds__(256) void rotary_kernel(unsigned short* __restrict__ qkv) {
  const int idx = blockIdx.x * blockDim.x + threadIdx.x;
  const int d = idx & 63;
  const int h = (idx >> 6) & (HH - 1);
  const int s = (idx >> 10) & (SS - 1);
  const int b = idx >> 21;

  const float inv_freq = powf(10000.0f, -(float)d / 64.0f);
  const float freq = (float)s * inv_freq;
  const float c = cosf(freq);
  const float sn = sinf(freq);

  const size_t base = ((size_t)b * SS + s) * FF + h * DD + d;
  unsigned short* q = qkv + base;
  unsigned short* k = qkv + base + EE;

  const float q1 = bf2f(q[0]), q2 = bf2f(q[64]);
  q[0]  = f2bf(q1 * c - q2 * sn);
  q[64] = f2bf(q2 * c + q1 * sn);
  const float k1 = bf2f(k[0]), k2 = bf2f(k[64]);
  k[0]  = f2bf(k1 * c - k2 * sn);
  k[64] = f2bf(k2 * c + k1 * sn);
}

// ---------------------------------------------------------------------------
// Flash-style causal attention (fp32 compute, bf16 in/out).
// ---------------------------------------------------------------------------
#define TQ 64
#define TK 32

static __device__ __forceinline__ void bf8_to_f32(const unsigned short* src,
                                                  float* dst) {
  const uint4 u = *(const uint4*)src;
  dst[0] = __uint_as_float(u.x << 16);
  dst[1] = __uint_as_float(u.x & 0xffff0000u);
  dst[2] = __uint_as_float(u.y << 16);
  dst[3] = __uint_as_float(u.y & 0xffff0000u);
  dst[4] = __uint_as_float(u.z << 16);
  dst[5] = __uint_as_float(u.z & 0xffff0000u);
  dst[6] = __uint_as_float(u.w << 16);
  dst[7] = __uint_as_float(u.w & 0xffff0000u);
}

__global__ __launch_bounds__(256) void attn_kernel(
    const unsigned short* __restrict__ qkv, unsigned short* __restrict__ ctx) {
  __shared__ float Ks[TK][DD];
  __shared__ float Vs[TK][DD];
  __shared__ float St[TK][TQ];

  const int qt = blockIdx.x;
  const int h  = blockIdx.y;
  const int b  = blockIdx.z;
  const int tid = threadIdx.x;
  const int r = tid >> 2;
  const int p = tid & 3;
  const int q0 = qt * TQ;
  const float scale = 0.08838834764831845f;

  float qreg[32];
  {
    const unsigned short* qp =
        qkv + ((size_t)b * SS + q0 + r) * FF + h * DD + p * 32;
#pragma unroll
    for (int jj = 0; jj < 4; ++jj) {
      float f[8];
      bf8_to_f32(qp + jj * 8, f);
#pragma unroll
      for (int t = 0; t < 8; ++t) qreg[jj * 8 + t] = f[t] * scale;
    }
  }

  float oacc[32] = {};
  float m_i = -INFINITY, l_i = 0.0f;

  const int lc = tid >> 3;
  const int lsub = (tid & 7) * 16;

  const int nkt = 2 * (qt + 1);
  for (int kt = 0; kt < nkt; ++kt) {
    const int k0 = kt * TK;
    {
      const unsigned short* kp =
          qkv + ((size_t)b * SS + k0 + lc) * FF + EE + h * DD + lsub;
      const unsigned short* vp = kp + EE;
      bf8_to_f32(kp, &Ks[lc][lsub]);
      bf8_to_f32(kp + 8, &Ks[lc][lsub + 8]);
      bf8_to_f32(vp, &Vs[lc][lsub]);
      bf8_to_f32(vp + 8, &Vs[lc][lsub + 8]);
    }
    __syncthreads();

    float tmax = -INFINITY;
    for (int c = 0; c < TK; ++c) {
      float partial = 0.0f;
      const float4* kr = (const float4*)&Ks[c][p * 32];
#pragma unroll
      for (int jj = 0; jj < 8; ++jj) {
        const float4 kv = kr[jj];
        partial += qreg[4 * jj] * kv.x + qreg[4 * jj + 1] * kv.y +
                   qreg[4 * jj + 2] * kv.z + qreg[4 * jj + 3] * kv.w;
      }
      partial += __shfl_xor(partial, 1);
      partial += __shfl_xor(partial, 2);
      const float sc = (k0 + c <= q0 + r) ? partial : -INFINITY;
      if (p == 0) St[c][r] = sc;
      tmax = fmaxf(tmax, sc);
    }

    const float mnew = fmaxf(m_i, tmax);
    const float alpha = expf(m_i - mnew);
    l_i *= alpha;
#pragma unroll
    for (int j = 0; j < 32; ++j) oacc[j] *= alpha;

    for (int c = 0; c < TK; ++c) {
      const float pv = expf(St[c][r] - mnew);
      l_i += pv;
      const float4* vr = (const float4*)&Vs[c][p * 32];
#pragma unroll
      for (int jj = 0; jj < 8; ++jj) {
        const float4 vv = vr[jj];
        oacc[4 * jj]     += pv * vv.x;
        oacc[4 * jj + 1] += pv * vv.y;
        oacc[4 * jj + 2] += pv * vv.z;
        oacc[4 * jj + 3] += pv * vv.w;
      }
    }
    m_i = mnew;
    __syncthreads();
  }

  const float inv_l = 1.0f / l_i;
  unsigned short* op = ctx + ((size_t)b * SS + q0 + r) * EE + h * DD + p * 32;
#pragma unroll
  for (int g = 0; g < 4; ++g) {  // 4 stores of 8 bf16 each
    uint4 u;
    u.x = (unsigned)f2bf(oacc[g * 8 + 0] * inv_l) |
          ((unsigned)f2bf(oacc[g * 8 + 1] * inv_l) << 16);
    u.y = (unsigned)f2bf(oacc[g * 8 + 2] * inv_l) |
          ((unsigned)f2bf(oacc[g * 8 + 3] * inv_l) << 16);
    u.z = (unsigned)f2bf(oacc[g * 8 + 4] * inv_l) |
          ((unsigned)f2bf(oacc[g * 8 + 5] * inv_l) << 16);
    u.w = (unsigned)f2bf(oacc[g * 8 + 6] * inv_l) |
          ((unsigned)f2bf(oacc[g * 8 + 7] * inv_l) << 16);
    *(uint4*)(op + g * 8) = u;
  }
}

// ---------------------------------------------------------------------------
// Launch
// ---------------------------------------------------------------------------
extern "C" void kernel_launch(void* const* d_in, const int* in_sizes, int n_in,
                              void* d_out, int out_size, void* d_ws,
                              size_t ws_size, hipStream_t stream) {
  const float* x    = (const float*)d_in[0];
  const float* wqkv = (const float*)d_in[1];
  const float* bqkv = (const float*)d_in[2];
  const float* wout = (const float*)d_in[3];
  const float* bout = (const float*)d_in[4];
  float* out = (float*)d_out;

  unsigned short* qkvb = (unsigned short*)d_ws;      // 25165824 elems
  unsigned short* xb   = qkvb + (size_t)25165824;    //  8388608
  unsigned short* wqb  = xb + (size_t)8388608;       // 12582912
  unsigned short* ctxb = wqb + (size_t)12582912;     //  8388608
  unsigned short* wob  = ctxb + (size_t)8388608;     //  4194304

  const int M = BB * SS;  // 4096

  cast_f32_bf16<<<8192, 256, 0, stream>>>(x, xb, 2097152);
  cast_f32_bf16<<<12288, 256, 0, stream>>>(wqkv, wqb, 3145728);
  cast_f32_bf16<<<4096, 256, 0, stream>>>(wout, wob, 1048576);

  {
    dim3 grid(FF / 128, M / 128);
    gemm_bf16_mfma<unsigned short><<<grid, 256, 0, stream>>>(
        xb, wqb, bqkv, qkvb, M, FF, EE);
  }
  {
    const int total = BB * SS * HH * 64;
    rotary_kernel<<<total / 256, 256, 0, stream>>>(qkvb);
  }
  {
    dim3 grid(SS / TQ, HH, BB);
    attn_kernel<<<grid, 256, 0, stream>>>(qkvb, ctxb);
  }
  {
    dim3 grid(EE / 128, M / 128);
    gemm_bf16_mfma<float><<<grid, 256, 0, stream>>>(
        ctxb, wob, bout, out, M, EE, EE);
  }
}

// Round 3
// 493.547 us; speedup vs baseline: 8.4754x; 5.0485x over previous
//
#include <hip/hip_runtime.h>
#include <math.h>

// Problem constants
#define BB 2
#define SS 2048
#define EE 2048
#define HH 16
#define DD 128
#define FF 6144   // 3*E

typedef __attribute__((ext_vector_type(8))) short short8;
typedef __attribute__((ext_vector_type(4))) float floatx4;

static __device__ __forceinline__ unsigned short f2bf(float x) {
  unsigned u = __float_as_uint(x);
  u += 0x7fffu + ((u >> 16) & 1u);
  return (unsigned short)(u >> 16);
}
static __device__ __forceinline__ float bf2f(unsigned short h) {
  return __uint_as_float((unsigned)h << 16);
}

#define GLOAD_LDS16(gp, lp)                                       \
  __builtin_amdgcn_global_load_lds(                               \
      (const __attribute__((address_space(1))) void*)(gp),        \
      (__attribute__((address_space(3))) void*)(lp), 16, 0, 0)

// ---------------------------------------------------------------------------
// fp32 -> bf16 cast (float4 in, ushort4 out)
// ---------------------------------------------------------------------------
__global__ __launch_bounds__(256) void cast_f32_bf16(
    const float* __restrict__ in, unsigned short* __restrict__ out, int n4) {
  const int i = blockIdx.x * 256 + threadIdx.x;
  if (i >= n4) return;
  const float4 v = ((const float4*)in)[i];
  ushort4 o;
  o.x = f2bf(v.x); o.y = f2bf(v.y); o.z = f2bf(v.z); o.w = f2bf(v.w);
  ((ushort4*)out)[i] = o;
}

// ---------------------------------------------------------------------------
// bf16 MFMA GEMM (m97 structure): C[m][n] = sum_k A[m][k]*Bt[n][k] + bias[n]
// ---------------------------------------------------------------------------
static __device__ __forceinline__ void store_out(float* p, float v) { *p = v; }
static __device__ __forceinline__ void store_out(unsigned short* p, float v) {
  *p = f2bf(v);
}

template <typename OutT>
__global__ __launch_bounds__(256) void gemm_bf16_mfma(
    const unsigned short* __restrict__ A, const unsigned short* __restrict__ Bt,
    const float* __restrict__ bias, OutT* __restrict__ C,
    int M, int N, int K) {
  __shared__ unsigned short As[128][32];
  __shared__ unsigned short Bs[128][32];
  const int tid = threadIdx.x;
  const int L = tid & 63;
  const int w = tid >> 6;
  const int m0 = blockIdx.y * 128;
  const int n0 = blockIdx.x * 128;

  const int i0 = w * 2;
  const int lrow = L >> 2;
  const int lcol = (L & 3) * 8;
  const size_t a_off0 = (size_t)(m0 + (i0 + 0) * 16 + lrow) * K + lcol;
  const size_t a_off1 = (size_t)(m0 + (i0 + 1) * 16 + lrow) * K + lcol;
  const size_t b_off0 = (size_t)(n0 + (i0 + 0) * 16 + lrow) * K + lcol;
  const size_t b_off1 = (size_t)(n0 + (i0 + 1) * 16 + lrow) * K + lcol;

  const int wr = (w >> 1) * 64;
  const int wc = (w & 1) * 64;
  const int lane16 = L & 15;
  const int quad = L >> 4;

  floatx4 acc[4][4] = {};

  for (int k0 = 0; k0 < K; k0 += 32) {
    __syncthreads();
    GLOAD_LDS16(A + a_off0 + k0, &As[(i0 + 0) * 16][0]);
    GLOAD_LDS16(A + a_off1 + k0, &As[(i0 + 1) * 16][0]);
    GLOAD_LDS16(Bt + b_off0 + k0, &Bs[(i0 + 0) * 16][0]);
    GLOAD_LDS16(Bt + b_off1 + k0, &Bs[(i0 + 1) * 16][0]);
    __syncthreads();

    short8 a[4], b[4];
#pragma unroll
    for (int mi = 0; mi < 4; ++mi)
      a[mi] = *(const short8*)(&As[wr + mi * 16 + lane16][quad * 8]);
#pragma unroll
    for (int ni = 0; ni < 4; ++ni)
      b[ni] = *(const short8*)(&Bs[wc + ni * 16 + lane16][quad * 8]);
#pragma unroll
    for (int mi = 0; mi < 4; ++mi)
#pragma unroll
      for (int ni = 0; ni < 4; ++ni)
        acc[mi][ni] = __builtin_amdgcn_mfma_f32_16x16x32_bf16(
            a[mi], b[ni], acc[mi][ni], 0, 0, 0);
  }

#pragma unroll
  for (int ni = 0; ni < 4; ++ni) {
    const int col = n0 + wc + ni * 16 + lane16;
    const float bv = bias[col];
#pragma unroll
    for (int mi = 0; mi < 4; ++mi) {
      const int row = m0 + wr + mi * 16 + quad * 4;
#pragma unroll
      for (int r = 0; r < 4; ++r)
        store_out(&C[(size_t)(row + r) * N + col], acc[mi][ni][r] + bv);
    }
  }
}

// ---------------------------------------------------------------------------
// Rotary on bf16 qkv in place. qkv layout [B][S][3][H][D] bf16.
// ---------------------------------------------------------------------------
__global__ __launch_bounds__(256) void rotary_kernel(unsigned short* __restrict__ qkv) {
  const int idx = blockIdx.x * blockDim.x + threadIdx.x;
  const int d = idx & 63;
  const int h = (idx >> 6) & (HH - 1);
  const int s = (idx >> 10) & (SS - 1);
  const int b = idx >> 21;

  const float inv_freq = powf(10000.0f, -(float)d / 64.0f);
  const float freq = (float)s * inv_freq;
  const float c = cosf(freq);
  const float sn = sinf(freq);

  const size_t base = ((size_t)b * SS + s) * FF + h * DD + d;
  unsigned short* q = qkv + base;
  unsigned short* k = qkv + base + EE;

  const float q1 = bf2f(q[0]), q2 = bf2f(q[64]);
  q[0]  = f2bf(q1 * c - q2 * sn);
  q[64] = f2bf(q2 * c + q1 * sn);
  const float k1 = bf2f(k[0]), k2 = bf2f(k[64]);
  k[0]  = f2bf(k1 * c - k2 * sn);
  k[64] = f2bf(k2 * c + k1 * sn);
}

// ---------------------------------------------------------------------------
// V transpose: qkv V slab [b][s][h][d] -> vt [b*H+h][d][s]   (bf16)
// 64(s) x 64(d) tiles via LDS.
// ---------------------------------------------------------------------------
__global__ __launch_bounds__(256) void transpose_v(
    const unsigned short* __restrict__ qkv, unsigned short* __restrict__ vt) {
  __shared__ unsigned short T[64][72];
  const int t = threadIdx.x;
  const int s0 = blockIdx.x * 64;
  const int d0 = blockIdx.y * 64;
  const int bh = blockIdx.z;
  const int b = bh >> 4, h = bh & 15;
  {
    const int r = t >> 2, c = (t & 3) * 16;
    const unsigned short* src =
        qkv + ((size_t)b * SS + s0 + r) * FF + 2 * EE + h * DD + d0 + c;
    const uint4 u0 = *(const uint4*)src;
    const uint4 u1 = *(const uint4*)(src + 8);
    *(uint4*)&T[r][c] = u0;
    *(uint4*)&T[r][c + 8] = u1;
  }
  __syncthreads();
  {
    const int rr = t >> 2, cc = (t & 3) * 16;
    unsigned short vals[16];
#pragma unroll
    for (int j = 0; j < 16; ++j) vals[j] = T[cc + j][rr];
    unsigned short* dst =
        vt + (size_t)bh * DD * SS + (size_t)(d0 + rr) * SS + s0 + cc;
    *(uint4*)dst = *(uint4*)&vals[0];
    *(uint4*)(dst + 8) = *(uint4*)&vals[8];
  }
}

// ---------------------------------------------------------------------------
// MFMA flash attention, causal.
// Block: 128 q rows (4 waves x 32 rows), K tiles of 64.
// K staged [kk][128] with XOR-swizzled 16B chunks; V^T staged [d][64] likewise.
// P round-trips through LDS (row stride 72) from C-layout to A-layout.
// LDS: 16KB (K) + 16KB (Vt) + 18KB (P) = 50KB.
// ---------------------------------------------------------------------------
#define ATQ 128
#define ATK 64

__global__ __launch_bounds__(256, 2) void attn_mfma(
    const unsigned short* __restrict__ qkv,
    const unsigned short* __restrict__ vt,
    unsigned short* __restrict__ ctx) {
  __shared__ __align__(16) unsigned short Ksh[64 * 128];
  __shared__ __align__(16) unsigned short Vsh[128 * 64];
  __shared__ __align__(16) unsigned short Ssh[128][72];

  const int tid = threadIdx.x;
  const int L = tid & 63;
  const int w = tid >> 6;
  const int lane16 = L & 15;
  const int quad = L >> 4;

  const int qb = (int)gridDim.x - 1 - (int)blockIdx.x;  // longest blocks first
  const int h = blockIdx.y;
  const int b = blockIdx.z;
  const int q0 = qb * ATQ;
  const int bh = b * HH + h;
  const float scale = 0.08838834764831845f;  // 1/sqrt(128)

  // Q a-frags: [mi][dc], A-layout m=lane16, k=quad*8+j
  short8 qf[2][4];
#pragma unroll
  for (int mi = 0; mi < 2; ++mi) {
    const int q = q0 + w * 32 + mi * 16 + lane16;
    const unsigned short* qp = qkv + ((size_t)b * SS + q) * FF + h * DD + quad * 8;
#pragma unroll
    for (int dc = 0; dc < 4; ++dc)
      qf[mi][dc] = *(const short8*)(qp + dc * 32);
  }

  // Staging address precompute.
  // K: instr j covers flat 16B-chunks F=(w*4+j)*64+L; row kk=F>>4, pos=L&15,
  //    global chunk cg = pos ^ (kk&15).
  size_t koff[4];
  // Vt: row d=F>>3 = (w*4+j)*8 + (L>>3); pos=L&7; cg=(L&7)^(L>>3).
  size_t voff[4];
#pragma unroll
  for (int j = 0; j < 4; ++j) {
    const int kk = (w * 4 + j) * 4 + quad;
    const int cgk = lane16 ^ (kk & 15);
    koff[j] = ((size_t)b * SS + kk) * FF + EE + h * DD + cgk * 8;
    const int d = (w * 4 + j) * 8 + (L >> 3);
    const int cgv = (L & 7) ^ (L >> 3);
    voff[j] = (size_t)bh * DD * SS + (size_t)d * SS + cgv * 8;
  }

  floatx4 acc[2][8] = {};
  float m_i[2][4], l_i[2][4];
#pragma unroll
  for (int mi = 0; mi < 2; ++mi)
#pragma unroll
    for (int r = 0; r < 4; ++r) { m_i[mi][r] = -3.0e38f; l_i[mi][r] = 0.0f; }

  const int nkt = (q0 + ATQ) / ATK;
  for (int kt = 0; kt < nkt; ++kt) {
    const int k0 = kt * ATK;
    __syncthreads();
#pragma unroll
    for (int j = 0; j < 4; ++j) {
      GLOAD_LDS16(qkv + koff[j] + (size_t)k0 * FF, Ksh + (w * 4 + j) * 512);
      GLOAD_LDS16(vt + voff[j] + k0, Vsh + (w * 4 + j) * 512);
    }
    __syncthreads();

    // --- QK^T: S[32 q][64 kk] per wave ---
    floatx4 s[2][4] = {};
#pragma unroll
    for (int nt = 0; nt < 4; ++nt) {
      const int kk = nt * 16 + lane16;
#pragma unroll
      for (int dc = 0; dc < 4; ++dc) {
        const int pos = (dc * 4 + quad) ^ lane16;
        const short8 kf = *(const short8*)(Ksh + kk * 128 + pos * 8);
#pragma unroll
        for (int mi = 0; mi < 2; ++mi)
          s[mi][nt] = __builtin_amdgcn_mfma_f32_16x16x32_bf16(
              qf[mi][dc], kf, s[mi][nt], 0, 0, 0);
      }
    }

    // --- scale + causal mask ---
    const bool needmask = (k0 + ATK - 1) > (q0 + w * 32);
#pragma unroll
    for (int mi = 0; mi < 2; ++mi) {
      const int qrow_base = q0 + w * 32 + mi * 16 + quad * 4;
#pragma unroll
      for (int nt = 0; nt < 4; ++nt) {
        const int kkc = k0 + nt * 16 + lane16;
#pragma unroll
        for (int r = 0; r < 4; ++r) {
          float v = s[mi][nt][r] * scale;
          if (needmask && kkc > qrow_base + r) v = -3.0e38f;
          s[mi][nt][r] = v;
        }
      }
    }

    // --- online softmax ---
    float mnew[2][4], alpha[2][4];
#pragma unroll
    for (int mi = 0; mi < 2; ++mi)
#pragma unroll
      for (int r = 0; r < 4; ++r) {
        float tm = fmaxf(fmaxf(s[mi][0][r], s[mi][1][r]),
                         fmaxf(s[mi][2][r], s[mi][3][r]));
        tm = fmaxf(tm, __shfl_xor(tm, 1));
        tm = fmaxf(tm, __shfl_xor(tm, 2));
        tm = fmaxf(tm, __shfl_xor(tm, 4));
        tm = fmaxf(tm, __shfl_xor(tm, 8));
        const float mn = fmaxf(m_i[mi][r], tm);
        mnew[mi][r] = mn;
        alpha[mi][r] = __expf(m_i[mi][r] - mn);
        m_i[mi][r] = mn;
      }

#pragma unroll
    for (int mi = 0; mi < 2; ++mi) {
#pragma unroll
      for (int r = 0; r < 4; ++r) {
        float rs = 0.0f;
#pragma unroll
        for (int nt = 0; nt < 4; ++nt) {
          const float p = __expf(s[mi][nt][r] - mnew[mi][r]);
          s[mi][nt][r] = p;
          rs += p;
        }
        rs += __shfl_xor(rs, 1);
        rs += __shfl_xor(rs, 2);
        rs += __shfl_xor(rs, 4);
        rs += __shfl_xor(rs, 8);
        l_i[mi][r] = l_i[mi][r] * alpha[mi][r] + rs;
      }
#pragma unroll
      for (int nt = 0; nt < 4; ++nt)
#pragma unroll
        for (int r = 0; r < 4; ++r)
          Ssh[w * 32 + mi * 16 + quad * 4 + r][nt * 16 + lane16] =
              f2bf(s[mi][nt][r]);
    }

    // rescale O accumulator
#pragma unroll
    for (int mi = 0; mi < 2; ++mi)
#pragma unroll
      for (int dt = 0; dt < 8; ++dt)
#pragma unroll
        for (int r = 0; r < 4; ++r) acc[mi][dt][r] *= alpha[mi][r];

    // --- PV: O[32 q][128 d] += P[32 q][64 kk] * V[64 kk][128 d] ---
#pragma unroll
    for (int kc = 0; kc < 2; ++kc) {
      short8 pa[2];
#pragma unroll
      for (int mi = 0; mi < 2; ++mi)
        pa[mi] = *(const short8*)(&Ssh[w * 32 + mi * 16 + lane16][kc * 32 + quad * 8]);
#pragma unroll
      for (int dt = 0; dt < 8; ++dt) {
        const int d = dt * 16 + lane16;
        const int pos = (kc * 4 + quad) ^ (d & 7);
        const short8 vf = *(const short8*)(Vsh + d * 64 + pos * 8);
#pragma unroll
        for (int mi = 0; mi < 2; ++mi)
          acc[mi][dt] = __builtin_amdgcn_mfma_f32_16x16x32_bf16(
              pa[mi], vf, acc[mi][dt], 0, 0, 0);
      }
    }
  }

  // epilogue: O / l -> ctx bf16 [b][s][h*128+d]
#pragma unroll
  for (int mi = 0; mi < 2; ++mi) {
#pragma unroll
    for (int r = 0; r < 4; ++r) {
      const int q = q0 + w * 32 + mi * 16 + quad * 4 + r;
      const float inv = 1.0f / l_i[mi][r];
      unsigned short* op = ctx + ((size_t)b * SS + q) * EE + h * DD + lane16;
#pragma unroll
      for (int dt = 0; dt < 8; ++dt)
        op[dt * 16] = f2bf(acc[mi][dt][r] * inv);
    }
  }
}

// ---------------------------------------------------------------------------
// Launch
// ---------------------------------------------------------------------------
extern "C" void kernel_launch(void* const* d_in, const int* in_sizes, int n_in,
                              void* d_out, int out_size, void* d_ws,
                              size_t ws_size, hipStream_t stream) {
  const float* x    = (const float*)d_in[0];
  const float* wqkv = (const float*)d_in[1];
  const float* bqkv = (const float*)d_in[2];
  const float* wout = (const float*)d_in[3];
  const float* bout = (const float*)d_in[4];
  float* out = (float*)d_out;

  unsigned short* qkvb = (unsigned short*)d_ws;      // 25165824 elems
  unsigned short* xb   = qkvb + (size_t)25165824;    //  8388608
  unsigned short* wqb  = xb + (size_t)8388608;       // 12582912
  unsigned short* ctxb = wqb + (size_t)12582912;     //  8388608
  unsigned short* wob  = ctxb + (size_t)8388608;     //  4194304
  unsigned short* vtb  = wob + (size_t)4194304;      //  8388608

  const int M = BB * SS;  // 4096

  cast_f32_bf16<<<8192, 256, 0, stream>>>(x, xb, 2097152);
  cast_f32_bf16<<<12288, 256, 0, stream>>>(wqkv, wqb, 3145728);
  cast_f32_bf16<<<4096, 256, 0, stream>>>(wout, wob, 1048576);

  {
    dim3 grid(FF / 128, M / 128);
    gemm_bf16_mfma<unsigned short><<<grid, 256, 0, stream>>>(
        xb, wqb, bqkv, qkvb, M, FF, EE);
  }
  {
    const int total = BB * SS * HH * 64;
    rotary_kernel<<<total / 256, 256, 0, stream>>>(qkvb);
  }
  {
    dim3 grid(SS / 64, DD / 64, BB * HH);
    transpose_v<<<grid, 256, 0, stream>>>(qkvb, vtb);
  }
  {
    dim3 grid(SS / ATQ, HH, BB);
    attn_mfma<<<grid, 256, 0, stream>>>(qkvb, vtb, ctxb);
  }
  {
    dim3 grid(EE / 128, M / 128);
    gemm_bf16_mfma<float><<<grid, 256, 0, stream>>>(
        ctxb, wob, bout, out, M, EE, EE);
  }
}